// Round 1
// baseline (57.177 us; speedup 1.0000x reference)
//
#include <hip/hip_runtime.h>
#include <math.h>

// Problem constants (fixed by harness)
#define NN   128
#define TT   1024
#define SS   1024
#define H1D  512
#define H2D  128
#define OUTD 8
#define TCH  4      // t-chunks for NUDFT split (occupancy)
#define TC   256    // t per chunk

// ws layout in floats (total ~6.03 MB)
#define OFF_RE   0
#define OFF_IM   (TCH*NN*SS)                  //  524288
#define OFF_FREQ (2*TCH*NN*SS)                // 1048576
#define OFF_P1   (OFF_FREQ + NN*SS)           // 1179648
#define OFF_H1   (OFF_P1 + 4*NN*H1D)          // 1441792  (end 1507328 floats)

__device__ __forceinline__ float cos_rev(float r) { return __builtin_amdgcn_cosf(r); } // cos(2*pi*r)
__device__ __forceinline__ float sin_rev(float r) { return __builtin_amdgcn_sinf(r); } // sin(2*pi*r)

// ---------------------------------------------------------------------------
// Kernel 1: partial NUDFT. Block = (t-chunk tc, batch n). Each thread owns 4
// consecutive s values; one hw sincos for base s, 3 angle-addition rotations
// using per-t (cos 2*pi*d, sin 2*pi*d) staged in LDS.
// Exact mod-1: frac(s*day) == frac(s*frac(day)); s*frac(day) split hi+lo via FMA.
// Sign of im irrelevant downstream (magnitude only).
// ---------------------------------------------------------------------------
__global__ __launch_bounds__(256) void k_nudft(const float* __restrict__ inp,
                                               float* __restrict__ ws) {
    const int tc  = blockIdx.x;   // 0..3
    const int n   = blockIdx.y;   // 0..127
    const int tid = threadIdx.x;  // 0..255

    __shared__ float4 sh[TC];     // {frac(day), x, cos(2pi d), sin(2pi d)}
    {
        const int t = tc * TC + tid;
        const float* p = inp + (size_t)(n * TT + t) * 3;
        const float x  = p[0];
        const float d  = p[2];
        const float df = d - floorf(d);            // exact (see analysis)
        sh[tid] = make_float4(df, x, cos_rev(df), sin_rev(df));
    }
    __syncthreads();

    const float s0f = (float)(tid * 4);
    float re0 = 0.f, re1 = 0.f, re2 = 0.f, re3 = 0.f;
    float im0 = 0.f, im1 = 0.f, im2 = 0.f, im3 = 0.f;

#pragma unroll 2
    for (int i = 0; i < TC; ++i) {
        const float4 v = sh[i];                    // broadcast read
        // r = frac(s0*df) with full fp32 precision of the fractional part
        const float p   = s0f * v.x;
        const float plo = fmaf(s0f, v.x, -p);      // exact product residual
        const float r   = (p - floorf(p)) + plo;
        float c  = cos_rev(r);
        float sn = sin_rev(r);
        re0 = fmaf(v.y, c, re0);  im0 = fmaf(v.y, sn, im0);
        // rotate by phi = 2*pi*df : (c,sn) <- (c*c1 - sn*s1, sn*c1 + c*s1)
        float c2  = fmaf(-sn, v.w, c * v.z);
        float sn2 = fmaf( c,  v.w, sn * v.z);
        re1 = fmaf(v.y, c2, re1); im1 = fmaf(v.y, sn2, im1);
        float c3  = fmaf(-sn2, v.w, c2 * v.z);
        float sn3 = fmaf( c2,  v.w, sn2 * v.z);
        re2 = fmaf(v.y, c3, re2); im2 = fmaf(v.y, sn3, im2);
        float c4  = fmaf(-sn3, v.w, c3 * v.z);
        float sn4 = fmaf( c3,  v.w, sn3 * v.z);
        re3 = fmaf(v.y, c4, re3); im3 = fmaf(v.y, sn4, im3);
    }

    const size_t base4 = (((size_t)(tc * NN + n)) * SS + tid * 4) >> 2;
    float4* RE = (float4*)(ws + OFF_RE);
    float4* IM = (float4*)(ws + OFF_IM);
    RE[base4] = make_float4(re0, re1, re2, re3);
    IM[base4] = make_float4(im0, im1, im2, im3);
}

// ---------------------------------------------------------------------------
// Kernel 2: combine t-chunk partials -> frequential = sqrt(re^2 + im^2)
// ---------------------------------------------------------------------------
__global__ __launch_bounds__(256) void k_combine1(float* __restrict__ ws) {
    const int tid = blockIdx.x * 256 + threadIdx.x;   // 0..131071 (= n*SS + s)
    const int n = tid >> 10, s = tid & 1023;
    float re = 0.f, im = 0.f;
    for (int tc = 0; tc < TCH; ++tc) {
        const size_t o = ((size_t)(tc * NN + n)) * SS + s;
        re += ws[OFF_RE + o];
        im += ws[OFF_IM + o];
    }
    ws[OFF_FREQ + tid] = sqrtf(fmaf(re, re, im * im));
}

// ---------------------------------------------------------------------------
// Kernel 3: layer-1 partial GEMM  h1pre = freq @ W1^T, split-K (4 chunks).
// Block: 8 n-rows x 128 j-cols over 256 k. Thread: (j, 4 n). A-tile in LDS
// (broadcast reads), W1 rows streamed from L2 (32 MB total traffic).
// ---------------------------------------------------------------------------
__global__ __launch_bounds__(256) void k_l1p(const float* __restrict__ W1,
                                             float* __restrict__ ws) {
    const int kq = blockIdx.x;   // 0..3   k-chunk of 256
    const int jq = blockIdx.y;   // 0..3   j-chunk of 128
    const int nb = blockIdx.z;   // 0..15  n-chunk of 8
    const int tid = threadIdx.x;

    __shared__ float4 Al[8][64];  // 8 n-rows x 256 k (as float4)
    const float4* FQ = (const float4*)(ws + OFF_FREQ);
#pragma unroll
    for (int v = 0; v < 2; ++v) {
        const int idx = v * 256 + tid;
        const int row = idx >> 6, c4 = idx & 63;
        Al[row][c4] = FQ[(nb * 8 + row) * 256 + kq * 64 + c4];
    }
    __syncthreads();

    const int jl = tid & 127, ng = tid >> 7;
    const int j = jq * 128 + jl;
    const float4* W1v = (const float4*)W1;
    float a0 = 0.f, a1 = 0.f, a2 = 0.f, a3 = 0.f;
#pragma unroll 4
    for (int k4 = 0; k4 < 64; ++k4) {
        const float4 w  = W1v[(size_t)j * 256 + kq * 64 + k4];
        const float4 x0 = Al[ng * 4 + 0][k4];
        const float4 x1 = Al[ng * 4 + 1][k4];
        const float4 x2 = Al[ng * 4 + 2][k4];
        const float4 x3 = Al[ng * 4 + 3][k4];
        a0 = fmaf(x0.x, w.x, fmaf(x0.y, w.y, fmaf(x0.z, w.z, fmaf(x0.w, w.w, a0))));
        a1 = fmaf(x1.x, w.x, fmaf(x1.y, w.y, fmaf(x1.z, w.z, fmaf(x1.w, w.w, a1))));
        a2 = fmaf(x2.x, w.x, fmaf(x2.y, w.y, fmaf(x2.z, w.z, fmaf(x2.w, w.w, a2))));
        a3 = fmaf(x3.x, w.x, fmaf(x3.y, w.y, fmaf(x3.z, w.z, fmaf(x3.w, w.w, a3))));
    }
    float* P1 = ws + OFF_P1;
    const float acc[4] = {a0, a1, a2, a3};
#pragma unroll
    for (int i = 0; i < 4; ++i)
        P1[((size_t)(kq * NN + nb * 8 + ng * 4 + i)) * H1D + j] = acc[i];
}

// ---------------------------------------------------------------------------
// Kernel 4: combine layer-1 split-K partials + bias + sigmoid -> h1
// ---------------------------------------------------------------------------
__global__ __launch_bounds__(256) void k_l1c(const float* __restrict__ b1,
                                             float* __restrict__ ws) {
    const int tid = blockIdx.x * 256 + threadIdx.x;   // 0..65535 (= n*H1D + j)
    const int j = tid & (H1D - 1);
    float s = b1[j];
    for (int kq = 0; kq < 4; ++kq) s += ws[OFF_P1 + (size_t)kq * (NN * H1D) + tid];
    ws[OFF_H1 + tid] = 1.0f / (1.0f + __expf(-s));
}

// ---------------------------------------------------------------------------
// Kernel 5: fused layers 2+3. Block per n; thread j<128 computes h2[j]; then
// 8 threads compute the final 8 outputs from LDS.
// ---------------------------------------------------------------------------
__global__ __launch_bounds__(128) void k_l23(const float* __restrict__ W2,
                                             const float* __restrict__ b2,
                                             const float* __restrict__ W3,
                                             const float* __restrict__ b3,
                                             const float* __restrict__ ws,
                                             float* __restrict__ out) {
    const int n = blockIdx.x;
    const int j = threadIdx.x;   // 0..127

    __shared__ float4 h1l[128];  // h1 row (512 floats)
    __shared__ float  h2l[128];
    h1l[j] = ((const float4*)(ws + OFF_H1))[n * 128 + j];
    __syncthreads();

    const float4* W2v = (const float4*)W2;
    float a = b2[j];
#pragma unroll 4
    for (int k = 0; k < 128; ++k) {
        const float4 h = h1l[k];                    // broadcast
        const float4 w = W2v[(size_t)j * 128 + k];
        a = fmaf(h.x, w.x, fmaf(h.y, w.y, fmaf(h.z, w.z, fmaf(h.w, w.w, a))));
    }
    h2l[j] = 1.0f / (1.0f + __expf(-a));
    __syncthreads();

    if (j < OUTD) {
        float acc = b3[j];
        for (int q = 0; q < H2D; ++q) acc = fmaf(h2l[q], W3[j * H2D + q], acc);
        out[n * OUTD + j] = acc;
    }
}

extern "C" void kernel_launch(void* const* d_in, const int* in_sizes, int n_in,
                              void* d_out, int out_size, void* d_ws, size_t ws_size,
                              hipStream_t stream) {
    (void)in_sizes; (void)n_in; (void)out_size; (void)ws_size;
    const float* inp = (const float*)d_in[0];
    const float* W1  = (const float*)d_in[1];
    const float* b1  = (const float*)d_in[2];
    const float* W2  = (const float*)d_in[3];
    const float* b2  = (const float*)d_in[4];
    const float* W3  = (const float*)d_in[5];
    const float* b3  = (const float*)d_in[6];
    float* out = (float*)d_out;
    float* ws  = (float*)d_ws;   // needs ~6.03 MB

    k_nudft   <<<dim3(TCH, NN), dim3(256), 0, stream>>>(inp, ws);
    k_combine1<<<dim3(512),     dim3(256), 0, stream>>>(ws);
    k_l1p     <<<dim3(4, 4, 16),dim3(256), 0, stream>>>(W1, ws);
    k_l1c     <<<dim3(256),     dim3(256), 0, stream>>>(b1, ws);
    k_l23     <<<dim3(128),     dim3(128), 0, stream>>>(W2, b2, W3, b3, ws, out);
}